// Round 3
// baseline (262.562 us; speedup 1.0000x reference)
//
#include <hip/hip_runtime.h>
#include <math.h>

#define NB 2
#define NL 2048
#define NK 32
#define NODE_F 128
#define EDGE_F 128

// output layout (float32 elements)
#define OFF_HV   0
#define OFF_HE   (NB*NL*NODE_F)                 // 524288
#define OFF_EIDX (OFF_HE + NB*NL*NK*EDGE_F)     // 17301504
#define OFF_X    (OFF_EIDX + NB*NL*NK)          // 17432576

typedef __attribute__((ext_vector_type(8))) short v8s;
typedef __attribute__((ext_vector_type(4))) float v4f;

__device__ __forceinline__ short f2bf(float f) {
    unsigned u = __float_as_uint(f);
    unsigned r = u + 0x7fffu + ((u >> 16) & 1u);
    return (short)(r >> 16);
}

// ---------------- helpers ----------------
__device__ __forceinline__ void cross3(const float a[3], const float b[3], float c[3]) {
    c[0] = a[1]*b[2] - a[2]*b[1];
    c[1] = a[2]*b[0] - a[0]*b[2];
    c[2] = a[0]*b[1] - a[1]*b[0];
}
__device__ __forceinline__ float dot3(const float a[3], const float b[3]) {
    return a[0]*b[0] + a[1]*b[1] + a[2]*b[2];
}
__device__ float dihedral_f(const float p0[3], const float p1[3],
                            const float p2[3], const float p3[3]) {
    float u0[3], u1[3], u2[3];
    for (int d = 0; d < 3; d++) {
        u0[d] = p2[d] - p1[d];
        u1[d] = p0[d] - p1[d];
        u2[d] = p3[d] - p2[d];
    }
    float n1[3], n2[3], c12[3];
    cross3(u0, u1, n1);
    cross3(u0, u2, n2);
    cross3(u1, u2, c12);
    float l1 = sqrtf(dot3(n1, n1));
    float l2 = sqrtf(dot3(n2, n2));
    float cosang = dot3(n1, n2) / (l1 * l2);
    float s = dot3(c12, u0);
    float sgn = (s > 0.f) ? 1.f : ((s < 0.f) ? -1.f : 0.f);
    float r = sgn * acosf(cosang);
    return isnan(r) ? 0.f : r;
}

// ---------------- kernel 0: W_edge RBF rows -> bf16 MFMA-fragment order ----------------
__global__ void wconv_kernel(const float* __restrict__ We, short* __restrict__ WTf) {
    int t = blockIdx.x * 256 + threadIdx.x;
    if (t >= 13 * 8 * 64) return;
    int lane = t & 63;
    int nt = (t >> 6) & 7;
    int ch = t >> 9;
    int n = nt * 16 + (lane & 15);
    int kbase = ch * 32 + (lane >> 4) * 8;
    short* dst = WTf + (size_t)t * 8;
#pragma unroll
    for (int j = 0; j < 8; j++) {
        int k = kbase + j;
        float f = (k < 400) ? We[(65 + k) * 128 + n] : 0.f;
        dst[j] = f2bf(f);
    }
}

// ---------------- kernel 1: X5 prep (N,Ca,C,O,Cb) + X passthrough ----------------
__global__ void prep_kernel(const float* __restrict__ X, float* __restrict__ X5,
                            float* __restrict__ out) {
    int row = blockIdx.x * blockDim.x + threadIdx.x;
    if (row >= NB * NL) return;
    float v[12];
#pragma unroll
    for (int t = 0; t < 12; t++) v[t] = X[row * 12 + t];
#pragma unroll
    for (int t = 0; t < 12; t++) out[OFF_X + row * 12 + t] = v[t];
    float bv[3], cv[3], cr[3];
    for (int d = 0; d < 3; d++) { bv[d] = v[3+d] - v[d]; cv[d] = v[6+d] - v[3+d]; }
    cross3(bv, cv, cr);
    float* x5 = X5 + row * 15;
#pragma unroll
    for (int t = 0; t < 12; t++) x5[t] = v[t];
    for (int d = 0; d < 3; d++)
        x5[12 + d] = -0.58273431f * cr[d] + 0.56802827f * bv[d] - 0.54067466f * cv[d] + v[3+d];
}

// ---------------- kernel 2: KNN v3 ----------------
// 256 threads = 4 waves; wave w -> (rowLocal = w>>1, half = w&1).
// Each wave: 16 candidates/lane over its 1024-candidate half, Batcher-sorted once,
// then 32 rounds of {wave-min of key[0]; owner shift-down}. Halves rank-merged.
#define CE(x,y) { unsigned long long _a = key[x], _b = key[y]; \
                  if (_a > _b) { key[x] = _b; key[y] = _a; } }

__global__ __launch_bounds__(256) void knn3_kernel(const float* __restrict__ X,
                                                   const float* __restrict__ mask,
                                                   int* __restrict__ EidxW,
                                                   float* __restrict__ out) {
    __shared__ float sCa[NL * 3];                     // 24 KB, shared by both rows
    __shared__ float sMaxHalf[2][2];
    __shared__ unsigned long long sList[2][64];

    int tid = threadIdx.x;
    int w = tid >> 6, l = tid & 63;
    int rowLocal = w >> 1, half = w & 1;
    int row = blockIdx.x * 2 + rowLocal;              // global row, both rows same batch
    int b = row / NL;

    for (int j = tid; j < NL; j += 256) {
        const float* p = X + ((size_t)(b * NL + j) * 4 + 1) * 3;  // Ca
        sCa[j * 3 + 0] = p[0];
        sCa[j * 3 + 1] = p[1];
        sCa[j * 3 + 2] = p[2];
    }
    __syncthreads();

    int iloc = row - b * NL;
    float cx = sCa[iloc * 3], cy = sCa[iloc * 3 + 1], cz = sCa[iloc * 3 + 2];
    float mi = mask[row];
    int jbase = half * 1024;

    unsigned long long key[16];
    float lmax = 0.0f;
#pragma unroll
    for (int t = 0; t < 16; t++) {
        int j = jbase + t * 64 + l;
        float dx = __fsub_rn(cx, sCa[j * 3 + 0]);
        float dy = __fsub_rn(cy, sCa[j * 3 + 1]);
        float dz = __fsub_rn(cz, sCa[j * 3 + 2]);
        float ss = __fadd_rn(__fadd_rn(__fadd_rn(__fmul_rn(dx, dx), __fmul_rn(dy, dy)),
                                       __fmul_rn(dz, dz)), 1e-6f);
        float d = __fmul_rn(__fmul_rn(mi, mask[b * NL + j]), __fsqrt_rn(ss));
        key[t] = (unsigned long long)__float_as_uint(d);   // stash d bits
        lmax = fmaxf(lmax, d);
    }
#pragma unroll
    for (int s = 1; s < 64; s <<= 1) lmax = fmaxf(lmax, __shfl_xor(lmax, s, 64));
    if (l == 0) sMaxHalf[rowLocal][half] = lmax;
    __syncthreads();
    float dmax = fmaxf(sMaxHalf[rowLocal][0], sMaxHalf[rowLocal][1]);

#pragma unroll
    for (int t = 0; t < 16; t++) {
        int j = jbase + t * 64 + l;
        float d = __uint_as_float((unsigned)key[t]);
        float m2 = __fmul_rn(mi, mask[b * NL + j]);
        float dadj = __fadd_rn(d, __fmul_rn(__fmul_rn(2.0f, __fsub_rn(1.0f, m2)), dmax));
        key[t] = (((unsigned long long)__float_as_uint(dadj)) << 32) | (unsigned)j;
    }

    // Batcher odd-even mergesort, n=16 (63 compare-exchanges), ascending
    CE(0,1) CE(2,3) CE(4,5) CE(6,7) CE(8,9) CE(10,11) CE(12,13) CE(14,15)
    CE(0,2) CE(1,3) CE(4,6) CE(5,7) CE(8,10) CE(9,11) CE(12,14) CE(13,15)
    CE(1,2) CE(5,6) CE(9,10) CE(13,14)
    CE(0,4) CE(1,5) CE(2,6) CE(3,7) CE(8,12) CE(9,13) CE(10,14) CE(11,15)
    CE(2,4) CE(3,5) CE(10,12) CE(11,13)
    CE(1,2) CE(3,4) CE(5,6) CE(9,10) CE(11,12) CE(13,14)
    CE(0,8) CE(1,9) CE(2,10) CE(3,11) CE(4,12) CE(5,13) CE(6,14) CE(7,15)
    CE(4,8) CE(5,9) CE(6,10) CE(7,11)
    CE(2,4) CE(3,5) CE(6,8) CE(7,9) CE(10,12) CE(11,13)
    CE(1,2) CE(3,4) CE(5,6) CE(7,8) CE(9,10) CE(11,12) CE(13,14)

    // 32 selection rounds
    unsigned long long sel = 0xFFFFFFFFFFFFFFFFull;
    for (int r = 0; r < NK; r++) {
        unsigned long long best = key[0];
#pragma unroll
        for (int s = 1; s < 64; s <<= 1) {
            unsigned long long o = __shfl_xor(best, s, 64);
            best = (o < best) ? o : best;
        }
        if (l == r) sel = best;
        if (key[0] == best) {   // exactly one lane (keys unique): shift down
#pragma unroll
            for (int t = 0; t < 15; t++) key[t] = key[t + 1];
            key[15] = 0xFFFFFFFFFFFFFFFFull;
        }
    }
    if (l < 32) sList[rowLocal][half * 32 + l] = sel;
    __syncthreads();

    // rank-merge the two sorted 32-lists (keys unique)
    if (half == 0) {
        unsigned long long mykey = sList[rowLocal][l];
        const unsigned long long* other = &sList[rowLocal][(l < 32) ? 32 : 0];
        int rank = l & 31;
#pragma unroll
        for (int t = 0; t < 32; t++) rank += (other[t] < mykey) ? 1 : 0;
        if (rank < NK) {
            int widx = (int)(mykey & 0xFFFFFFFFull);
            EidxW[row * NK + rank] = widx;
            out[OFF_EIDX + row * NK + rank] = (float)widx;
        }
    }
}

// ---------------- kernel 3: node features + LN (one wave per row, shfl-only) ----------------
__global__ __launch_bounds__(256) void node2_kernel(const int* __restrict__ S,
                                                    const float* __restrict__ BB,
                                                    const float* __restrict__ SC,
                                                    const float* __restrict__ Wn,
                                                    const float* __restrict__ bn,
                                                    const float* __restrict__ gn,
                                                    const float* __restrict__ betan,
                                                    float* __restrict__ out) {
    int tid = threadIdx.x;
    int w = tid >> 6, l = tid & 64 - 1;
    int row = blockIdx.x * 4 + w;
    int f0 = l, f1 = 64 + l;
    int s = S[row];
    float a0 = bn[f0] + Wn[s * NODE_F + f0];
    float a1 = bn[f1] + Wn[s * NODE_F + f1];
#pragma unroll
    for (int t = 0; t < 6; t++) {
        float x = BB[row * 6 + t];
        a0 += x * Wn[(21 + t) * NODE_F + f0];
        a1 += x * Wn[(21 + t) * NODE_F + f1];
    }
#pragma unroll
    for (int t = 0; t < 8; t++) {
        float x = SC[row * 8 + t];
        a0 += x * Wn[(27 + t) * NODE_F + f0];
        a1 += x * Wn[(27 + t) * NODE_F + f1];
    }
    float sm = a0 + a1;
#pragma unroll
    for (int st = 1; st < 64; st <<= 1) sm += __shfl_xor(sm, st, 64);
    float mean = sm * (1.0f / 128.0f);
    float d0 = a0 - mean, d1 = a1 - mean;
    float q = d0 * d0 + d1 * d1;
#pragma unroll
    for (int st = 1; st < 64; st <<= 1) q += __shfl_xor(q, st, 64);
    float rstd = 1.0f / sqrtf(q * (1.0f / 128.0f) + 1e-5f);
    out[OFF_HV + row * NODE_F + f0] = d0 * rstd * gn[f0] + betan[f0];
    out[OFF_HV + row * NODE_F + f1] = d1 * rstd * gn[f1] + betan[f1];
}

// ---------------- kernel 4: fused edge features + bf16 MFMA GEMM + LN ----------------
__global__ __launch_bounds__(256) void edge2_kernel(const float* __restrict__ X5,
                                                    const int* __restrict__ Eidx,
                                                    const int* __restrict__ chain,
                                                    const float* __restrict__ We,
                                                    const float* __restrict__ be,
                                                    const float* __restrict__ ge,
                                                    const float* __restrict__ betae,
                                                    const short* __restrict__ WTf,
                                                    float* __restrict__ out) {
    __shared__ float sXi[2][15];
    __shared__ float sXj[64][16];
    __shared__ int sJ[64];
    __shared__ int sPos[64];
    __shared__ float sEt[64], sPhi[64], sPsi[64];
    __shared__ float sDn[25][64];
    __shared__ __attribute__((aligned(16))) short sW[4096];
    __shared__ float sRow[6][128];

    int tid = threadIdx.x;
    int e0 = blockIdx.x * 64;
    int b = e0 / (NL * NK);
    int i0 = (e0 / NK) % NL;

    if (tid < 64) sJ[tid] = Eidx[e0 + tid];
    if (tid < 30) sXi[tid / 15][tid % 15] = X5[(b * NL + i0 + tid / 15) * 15 + (tid % 15)];
    for (int t = tid; t < 6 * 128; t += 256) {
        int rr = t >> 7, n2 = t & 127;
        float v;
        if (rr < 3) v = We[(465 + rr) * 128 + n2];
        else if (rr == 3) v = be[n2];
        else if (rr == 4) v = ge[n2];
        else v = betae[n2];
        sRow[rr][n2] = v;
    }
    __syncthreads();
    for (int t = tid; t < 64 * 15; t += 256) {
        int e = t / 15, c2 = t % 15;
        sXj[e][c2] = X5[(b * NL + sJ[e]) * 15 + c2];
    }
    if (tid < 64) {
        int e = tid;
        int i = i0 + (e >> 5);
        int j = sJ[e];
        int off = j - i + 32;
        off = off < 0 ? 0 : (off > 64 ? 64 : off);
        sPos[e] = off;
        sEt[e] = (chain[b * NL + j] == chain[b * NL + i]) ? 2.0f : 1.0f;
    }
    __syncthreads();
    for (int t = tid; t < 1600; t += 256) {
        int p = t >> 6, e = t & 63;
        int a = p / 5, c2 = p - a * 5;
        const float* xi = &sXi[e >> 5][a * 3];
        const float* xj = &sXj[e][c2 * 3];
        float dx = xi[0] - xj[0], dy = xi[1] - xj[1], dz = xi[2] - xj[2];
        sDn[p][e] = sqrtf(dx * dx + dy * dy + dz * dz + 1e-6f);
    }
    if (tid < 64) {
        int e = tid;
        const float* xi = sXi[e >> 5];
        const float* xj = sXj[e];
        sPhi[e] = dihedral_f(&xi[6], &xj[0], &xj[3], &xj[6]);
        sPsi[e] = dihedral_f(&xi[0], &xi[3], &xi[6], &xj[0]);
    }
    const int4* gsrc = (const int4*)WTf;
    int4 r0 = gsrc[tid], r1 = gsrc[tid + 256];
    __syncthreads();

    int lane = tid & 63, w = tid >> 6;
    int c = lane & 15, kq = lane >> 4;
    int eA = w * 16 + c;
    v4f acc[8];
#pragma unroll
    for (int nt = 0; nt < 8; nt++) acc[nt] = (v4f){0.f, 0.f, 0.f, 0.f};

    int4* sW4 = (int4*)sW;
    for (int ch = 0; ch < 13; ch++) {
        sW4[tid] = r0;
        sW4[tid + 256] = r1;
        __syncthreads();
        if (ch < 12) {
            r0 = gsrc[(ch + 1) * 512 + tid];
            r1 = gsrc[(ch + 1) * 512 + tid + 256];
        }
        int pair = 2 * ch + (kq >> 1);
        float d = sDn[pair < 25 ? pair : 24][eA];
        v8s a;
#pragma unroll
        for (int j = 0; j < 8; j++) {
            float mu = (float)((kq & 1) * 8 + j) * (20.0f / 15.0f);
            float x = (d - mu) * 0.8f;
            float rv = (pair < 25) ? __expf(-x * x) : 0.f;
            a[j] = f2bf(rv);
        }
#pragma unroll
        for (int nt = 0; nt < 8; nt++) {
            v8s bfr = *(const v8s*)(sW + ((nt * 64 + lane) << 3));
            acc[nt] = __builtin_amdgcn_mfma_f32_16x16x32_bf16(a, bfr, acc[nt], 0, 0, 0);
        }
        __syncthreads();
    }

#pragma unroll
    for (int r = 0; r < 4; r++) {
        int m = kq * 4 + r;
        int e = w * 16 + m;
        float ph = sPhi[e], ps = sPsi[e], et = sEt[e];
        int pos = sPos[e];
        float vals[8];
        float s = 0.f, q2 = 0.f;
#pragma unroll
        for (int nt = 0; nt < 8; nt++) {
            int n = nt * 16 + c;
            float v = acc[nt][r] + sRow[3][n] + We[pos * 128 + n]
                    + et * sRow[0][n] + ph * sRow[1][n] + ps * sRow[2][n];
            vals[nt] = v;
            s += v;
            q2 += v * v;
        }
#pragma unroll
        for (int s2 = 1; s2 < 16; s2 <<= 1) {
            s  += __shfl_xor(s,  s2, 64);
            q2 += __shfl_xor(q2, s2, 64);
        }
        float mean = s * (1.0f / 128.0f);
        float var = q2 * (1.0f / 128.0f) - mean * mean;
        float rstd = rsqrtf(var + 1e-5f);
#pragma unroll
        for (int nt = 0; nt < 8; nt++) {
            int n = nt * 16 + c;
            out[OFF_HE + (size_t)(e0 + e) * 128 + n] =
                (vals[nt] - mean) * rstd * sRow[4][n] + sRow[5][n];
        }
    }
}

// ---------------- launch ----------------
extern "C" void kernel_launch(void* const* d_in, const int* in_sizes, int n_in,
                              void* d_out, int out_size, void* d_ws, size_t ws_size,
                              hipStream_t stream) {
    (void)in_sizes; (void)n_in; (void)out_size; (void)ws_size;
    const float* X    = (const float*)d_in[0];
    const int*   S    = (const int*)d_in[1];
    const float* BB   = (const float*)d_in[2];
    const float* SC   = (const float*)d_in[3];
    const int*   chain= (const int*)d_in[4];
    const float* mask = (const float*)d_in[5];
    const float* Wn   = (const float*)d_in[6];
    const float* bn   = (const float*)d_in[7];
    const float* gn   = (const float*)d_in[8];
    const float* betan= (const float*)d_in[9];
    const float* We   = (const float*)d_in[10];
    const float* be   = (const float*)d_in[11];
    const float* ge   = (const float*)d_in[12];
    const float* betae= (const float*)d_in[13];
    float* out = (float*)d_out;

    char* ws = (char*)d_ws;
    int*   EidxW = (int*)ws;                                  // 524288 B
    float* X5    = (float*)(ws + 524288);                     // 245760 B
    short* WTf   = (short*)(ws + 524288 + 245760);            // 106496 B

    hipLaunchKernelGGL(wconv_kernel, dim3(26), dim3(256), 0, stream, We, WTf);
    hipLaunchKernelGGL(prep_kernel, dim3((NB * NL + 255) / 256), dim3(256), 0, stream,
                       X, X5, out);
    hipLaunchKernelGGL(knn3_kernel, dim3(NB * NL / 2), dim3(256), 0, stream,
                       X, mask, EidxW, out);
    hipLaunchKernelGGL(node2_kernel, dim3(NB * NL / 4), dim3(256), 0, stream,
                       S, BB, SC, Wn, bn, gn, betan, out);
    hipLaunchKernelGGL(edge2_kernel, dim3(NB * NL * NK / 64), dim3(256), 0, stream,
                       X5, EidxW, chain, We, be, ge, betae, WTf, out);
}